// Round 3
// baseline (214.774 us; speedup 1.0000x reference)
//
#include <hip/hip_runtime.h>
#include <hip/hip_bf16.h>
#include <stdint.h>

#define BROWS 4096
#define DDIM  1024

typedef __bf16 bf16_t;
typedef __bf16 bf16x8 __attribute__((ext_vector_type(8)));
typedef float  f32x4  __attribute__((ext_vector_type(4)));

__device__ __forceinline__ unsigned short f2bf_bits(float f) {
    union { float f; unsigned int u; } v; v.f = f;
    unsigned int u = v.u;
    unsigned int r = (u + 0x7fffu + ((u >> 16) & 1u)) >> 16;
    return (unsigned short)r;
}

// ---------------------------------------------------------------------------
// Kernel 1: prep — per row: log(q)->bf16, p->bf16, e[row]=sum p*log p,
//           kl_div[row]=mean p*(log p - log q); zero CS/CL/EL[row];
//           AND build label bitmask Lb[row][j/64] via __ballot (L is {0,1}).
// ---------------------------------------------------------------------------
__global__ __launch_bounds__(256) void prep_kernel(
    const float* __restrict__ q, const float* __restrict__ p,
    const float* __restrict__ L,
    bf16_t* __restrict__ lqb, bf16_t* __restrict__ pb,
    uint64_t* __restrict__ Lb,
    float* __restrict__ e, float* __restrict__ kld,
    float* __restrict__ CS, float* __restrict__ CL, float* __restrict__ EL)
{
    const int row = blockIdx.x;
    const int t   = threadIdx.x;
    const int wv  = t >> 6, ln = t & 63;

    const float4* q4 = (const float4*)(q + (size_t)row * DDIM);
    const float4* p4 = (const float4*)(p + (size_t)row * DDIM);
    float4 qv = q4[t];
    float4 pv = p4[t];

    float lq0 = __logf(qv.x), lq1 = __logf(qv.y), lq2 = __logf(qv.z), lq3 = __logf(qv.w);
    float lp0 = __logf(pv.x), lp1 = __logf(pv.y), lp2 = __logf(pv.z), lp3 = __logf(pv.w);

    float esum = pv.x * lp0 + pv.y * lp1 + pv.z * lp2 + pv.w * lp3;
    float ksum = pv.x * (lp0 - lq0) + pv.y * (lp1 - lq1)
               + pv.z * (lp2 - lq2) + pv.w * (lp3 - lq3);

    ushort4 uq, up;
    uq.x = f2bf_bits(lq0); uq.y = f2bf_bits(lq1); uq.z = f2bf_bits(lq2); uq.w = f2bf_bits(lq3);
    up.x = f2bf_bits(pv.x); up.y = f2bf_bits(pv.y); up.z = f2bf_bits(pv.z); up.w = f2bf_bits(pv.w);
    ((ushort4*)(lqb + (size_t)row * DDIM))[t] = uq;
    ((ushort4*)(pb  + (size_t)row * DDIM))[t] = up;

    // labels row -> 64 uint64 bitmask words (bit j = L[row][j] != 0)
    const float* Lrow = L + (size_t)row * BROWS;
    #pragma unroll
    for (int c = 0; c < 16; c++) {
        float v = Lrow[c * 256 + t];
        unsigned long long m = __ballot(v != 0.0f);
        if (ln == 0) Lb[(size_t)row * 64 + c * 4 + wv] = m;
    }

    if (t == 0) { CS[row] = 0.f; CL[row] = 0.f; EL[row] = 0.f; }

    #pragma unroll
    for (int off = 32; off > 0; off >>= 1) {
        esum += __shfl_down(esum, off);
        ksum += __shfl_down(ksum, off);
    }
    __shared__ float se[4], sk[4];
    if (ln == 0) { se[wv] = esum; sk[wv] = ksum; }
    __syncthreads();
    if (t == 0) {
        e[row]   = se[0] + se[1] + se[2] + se[3];
        kld[row] = (sk[0] + sk[1] + sk[2] + sk[3]) * (1.0f / DDIM);
    }
}

// ---------------------------------------------------------------------------
// Kernel 2: cross = log_q @ p^T, 64x64 tile, SINGLE-WAVE workgroup (64 thr),
//   NO BARRIERS — wave-local vmcnt ordering only; 4096 blocks for latency
//   hiding via TLP. Epilogue uses the 2 MB L2-resident bitmask.
// ---------------------------------------------------------------------------
__global__ __launch_bounds__(64, 4) void gemm_epi_kernel(
    const bf16_t* __restrict__ Abf,   // log_q [B,D]
    const bf16_t* __restrict__ Bbf,   // p     [B,D]
    const uint64_t* __restrict__ Lb,  // [B, B/64] bitmask
    const float*  __restrict__ e,     // [B]
    float* __restrict__ CS, float* __restrict__ CL, float* __restrict__ EL)
{
    __shared__ bf16_t As[64 * 32];   // 4 KB
    __shared__ bf16_t Bs[64 * 32];   // 4 KB

    const int lane = threadIdx.x;    // 0..63, one wave
    const int i0   = blockIdx.y * 64;
    const int j0   = blockIdx.x * 64;
    const int q4   = lane >> 4;
    const int ln   = lane & 15;

    f32x4 acc[4][4];
    #pragma unroll
    for (int a = 0; a < 4; a++)
        #pragma unroll
        for (int b = 0; b < 4; b++)
            acc[a][b] = (f32x4){0.f, 0.f, 0.f, 0.f};

    // staging: 64x32 bf16 tile = 256 x 16B chunks; 64 lanes x 4 instrs
    const bf16_t* gA[4];
    const bf16_t* gB[4];
    int ldsoff[4];
    #pragma unroll
    for (int n = 0; n < 4; n++) {
        const int c = n * 64 + lane;
        const int r = c >> 2;            // row 0..63
        const int col = (c & 3) * 8;     // element col 0/8/16/24
        gA[n] = Abf + (size_t)(i0 + r) * DDIM + col;
        gB[n] = Bbf + (size_t)(j0 + r) * DDIM + col;
        ldsoff[n] = c * 8;               // elements
    }

    #pragma unroll 1
    for (int k0 = 0; k0 < DDIM; k0 += 32) {
        #pragma unroll
        for (int n = 0; n < 4; n++)
            __builtin_amdgcn_global_load_lds(
                (const __attribute__((address_space(1))) void*)(gA[n] + k0),
                (__attribute__((address_space(3))) void*)(As + ldsoff[n]), 16, 0, 0);
        #pragma unroll
        for (int n = 0; n < 4; n++)
            __builtin_amdgcn_global_load_lds(
                (const __attribute__((address_space(1))) void*)(gB[n] + k0),
                (__attribute__((address_space(3))) void*)(Bs + ldsoff[n]), 16, 0, 0);
        // wave-local vmcnt wait inserted by compiler; no s_barrier

        bf16x8 af[4], bfr[4];
        #pragma unroll
        for (int mi = 0; mi < 4; mi++)
            af[mi] = *(const bf16x8*)(As + (mi * 16 + ln) * 32 + q4 * 8);
        #pragma unroll
        for (int ni = 0; ni < 4; ni++)
            bfr[ni] = *(const bf16x8*)(Bs + (ni * 16 + ln) * 32 + q4 * 8);
        #pragma unroll
        for (int mi = 0; mi < 4; mi++)
            #pragma unroll
            for (int ni = 0; ni < 4; ni++)
                acc[mi][ni] = __builtin_amdgcn_mfma_f32_16x16x32_bf16(
                    af[mi], bfr[ni], acc[mi][ni], 0, 0, 0);
    }

    // ---- epilogue: C/D layout col = lane&15 (=j), row = quad*4 + reg (=i) ----
    float e_j[4];
    #pragma unroll
    for (int ni = 0; ni < 4; ni++) e_j[ni] = e[j0 + ni * 16 + ln];

    #pragma unroll
    for (int mi = 0; mi < 4; mi++) {
        #pragma unroll
        for (int r = 0; r < 4; r++) {
            const int i = i0 + mi * 16 + q4 * 4 + r;
            const uint64_t m  = Lb[(size_t)i * 64 + (j0 >> 6)];
            const uint64_t ms = m >> ln;     // bit ni*16 now selects column ni*16+ln
            float cs = 0.f, cl = 0.f, el = 0.f;
            #pragma unroll
            for (int ni = 0; ni < 4; ni++) {
                float c = acc[mi][ni][r];
                cs += c;
                if ((ms >> (ni * 16)) & 1ull) { cl += c; el += e_j[ni]; }
            }
            #pragma unroll
            for (int s = 1; s < 16; s <<= 1) {
                cs += __shfl_xor(cs, s);
                cl += __shfl_xor(cl, s);
                el += __shfl_xor(el, s);
            }
            if (ln == 0) {
                atomicAdd(&CS[i], cs);
                atomicAdd(&CL[i], cl);
                atomicAdd(&EL[i], el);
            }
        }
    }
}

// ---------------------------------------------------------------------------
// Kernel 3: final — Etot = sum e; result = sum_i pos/neg
// ---------------------------------------------------------------------------
__global__ __launch_bounds__(256) void final_kernel(
    const float* __restrict__ e, const float* __restrict__ kld,
    const float* __restrict__ CS, const float* __restrict__ CL,
    const float* __restrict__ EL, float* __restrict__ out)
{
    __shared__ float sred[4];
    __shared__ float sEtot;
    const int t = threadIdx.x;

    float s = 0.f;
    for (int j = t; j < BROWS; j += 256) s += e[j];
    #pragma unroll
    for (int off = 32; off > 0; off >>= 1) s += __shfl_down(s, off);
    if ((t & 63) == 0) sred[t >> 6] = s;
    __syncthreads();
    if (t == 0) sEtot = sred[0] + sred[1] + sred[2] + sred[3];
    __syncthreads();
    const float Etot = sEtot;
    const float invD = 1.0f / DDIM;

    float rs = 0.f;
    for (int i = t; i < BROWS; i += 256) {
        float el = EL[i], cl = CL[i], cs = CS[i];
        float pos = kld[i] + (el - cl) * invD;
        float neg = (Etot - el - cs + cl) * invD;
        rs += pos / neg;
    }
    __syncthreads();
    #pragma unroll
    for (int off = 32; off > 0; off >>= 1) rs += __shfl_down(rs, off);
    if ((t & 63) == 0) sred[t >> 6] = rs;
    __syncthreads();
    if (t == 0) out[0] = sred[0] + sred[1] + sred[2] + sred[3];
}

// ---------------------------------------------------------------------------
extern "C" void kernel_launch(void* const* d_in, const int* in_sizes, int n_in,
                              void* d_out, int out_size, void* d_ws, size_t ws_size,
                              hipStream_t stream)
{
    const float* q = (const float*)d_in[0];
    const float* p = (const float*)d_in[1];
    const float* L = (const float*)d_in[2];
    float* out = (float*)d_out;

    char* ws = (char*)d_ws;
    bf16_t* lqb = (bf16_t*)ws;                                    // 8 MB
    bf16_t* pb  = (bf16_t*)(ws + (size_t)BROWS * DDIM * 2);       // 8 MB
    float*  e   = (float*)(ws + (size_t)BROWS * DDIM * 4);        // 16 KB
    float*  kld = e + BROWS;
    float*  CS  = kld + BROWS;
    float*  CL  = CS + BROWS;
    float*  EL  = CL + BROWS;
    uint64_t* Lb = (uint64_t*)(EL + BROWS);                       // 2 MB

    prep_kernel<<<BROWS, 256, 0, stream>>>(q, p, L, lqb, pb, Lb, e, kld, CS, CL, EL);

    dim3 grid(BROWS / 64, BROWS / 64);
    gemm_epi_kernel<<<grid, 64, 0, stream>>>(lqb, pb, Lb, e, CS, CL, EL);

    final_kernel<<<1, 256, 0, stream>>>(e, kld, CS, CL, EL, out);
}

// Round 4
// 190.355 us; speedup vs baseline: 1.1283x; 1.1283x over previous
//
#include <hip/hip_runtime.h>
#include <hip/hip_bf16.h>
#include <stdint.h>

#define BROWS 4096
#define DDIM  1024

typedef __bf16 bf16_t;
typedef __bf16 bf16x8 __attribute__((ext_vector_type(8)));
typedef float  f32x4  __attribute__((ext_vector_type(4)));

#define LDS_STRIDE 68   // 64 + 4 pad: bank stride 34 ≡ 2 (mod 32) → conflict-free b128 r/w

__device__ __forceinline__ unsigned short f2bf_bits(float f) {
    union { float f; unsigned int u; } v; v.f = f;
    unsigned int u = v.u;
    unsigned int r = (u + 0x7fffu + ((u >> 16) & 1u)) >> 16;
    return (unsigned short)r;
}

// ---------------------------------------------------------------------------
// Kernel 1: prep — log(q)->bf16, p->bf16, e[row], kl_div[row], zero CS/CL/EL,
//           label bitmask Lb[row][j/64] via __ballot.
// ---------------------------------------------------------------------------
__global__ __launch_bounds__(256) void prep_kernel(
    const float* __restrict__ q, const float* __restrict__ p,
    const float* __restrict__ L,
    bf16_t* __restrict__ lqb, bf16_t* __restrict__ pb,
    uint64_t* __restrict__ Lb,
    float* __restrict__ e, float* __restrict__ kld,
    float* __restrict__ CS, float* __restrict__ CL, float* __restrict__ EL)
{
    const int row = blockIdx.x;
    const int t   = threadIdx.x;
    const int wv  = t >> 6, ln = t & 63;

    const float4* q4 = (const float4*)(q + (size_t)row * DDIM);
    const float4* p4 = (const float4*)(p + (size_t)row * DDIM);
    float4 qv = q4[t];
    float4 pv = p4[t];

    float lq0 = __logf(qv.x), lq1 = __logf(qv.y), lq2 = __logf(qv.z), lq3 = __logf(qv.w);
    float lp0 = __logf(pv.x), lp1 = __logf(pv.y), lp2 = __logf(pv.z), lp3 = __logf(pv.w);

    float esum = pv.x * lp0 + pv.y * lp1 + pv.z * lp2 + pv.w * lp3;
    float ksum = pv.x * (lp0 - lq0) + pv.y * (lp1 - lq1)
               + pv.z * (lp2 - lq2) + pv.w * (lp3 - lq3);

    ushort4 uq, up;
    uq.x = f2bf_bits(lq0); uq.y = f2bf_bits(lq1); uq.z = f2bf_bits(lq2); uq.w = f2bf_bits(lq3);
    up.x = f2bf_bits(pv.x); up.y = f2bf_bits(pv.y); up.z = f2bf_bits(pv.z); up.w = f2bf_bits(pv.w);
    ((ushort4*)(lqb + (size_t)row * DDIM))[t] = uq;
    ((ushort4*)(pb  + (size_t)row * DDIM))[t] = up;

    const float* Lrow = L + (size_t)row * BROWS;
    #pragma unroll
    for (int c = 0; c < 16; c++) {
        float v = Lrow[c * 256 + t];
        unsigned long long m = __ballot(v != 0.0f);
        if (ln == 0) Lb[(size_t)row * 64 + c * 4 + wv] = m;
    }

    if (t == 0) { CS[row] = 0.f; CL[row] = 0.f; EL[row] = 0.f; }

    #pragma unroll
    for (int off = 32; off > 0; off >>= 1) {
        esum += __shfl_down(esum, off);
        ksum += __shfl_down(ksum, off);
    }
    __shared__ float se[4], sk[4];
    if (ln == 0) { se[wv] = esum; sk[wv] = ksum; }
    __syncthreads();
    if (t == 0) {
        e[row]   = se[0] + se[1] + se[2] + se[3];
        kld[row] = (sk[0] + sk[1] + sk[2] + sk[3]) * (1.0f / DDIM);
    }
}

// ---------------------------------------------------------------------------
// Kernel 2: cross = log_q @ p^T. Tile 256x128, 512 threads (8 waves, each
//   64x64), K-chunk=64. REGISTER-PREFETCH double buffer: global->VGPR loads
//   for chunk c+1 issued before compute of chunk c; vmcnt wait attaches to
//   next chunk's ds_write (full compute phase of slack). LDS stride 68
//   => conflict-free b128 reads AND writes. 2 blocks/CU.
// ---------------------------------------------------------------------------
__global__ __launch_bounds__(512, 4) void gemm_epi_kernel(
    const bf16_t* __restrict__ Abf,   // log_q [B,D]
    const bf16_t* __restrict__ Bbf,   // p     [B,D]
    const uint64_t* __restrict__ Lb,  // [B, B/64] bitmask
    const float*  __restrict__ e,     // [B]
    float* __restrict__ CS, float* __restrict__ CL, float* __restrict__ EL)
{
    __shared__ __align__(16) bf16_t As[256 * LDS_STRIDE];  // 34 KB
    __shared__ __align__(16) bf16_t Bs[128 * LDS_STRIDE];  // 17 KB

    const int t    = threadIdx.x;
    const int i0   = blockIdx.y * 256;
    const int j0   = blockIdx.x * 128;
    const int wave = t >> 6;
    const int lane = t & 63;
    const int q4   = lane >> 4;
    const int ln   = lane & 15;
    const int wrow = wave & 3;    // 4 i-subtiles
    const int wcol = wave >> 2;   // 2 j-subtiles

    f32x4 acc[4][4];
    #pragma unroll
    for (int a = 0; a < 4; a++)
        #pragma unroll
        for (int b = 0; b < 4; b++)
            acc[a][b] = (f32x4){0.f, 0.f, 0.f, 0.f};

    // staging maps: A chunk 256x64 = 2048 16B-chunks (4/thread);
    //               B chunk 128x64 = 1024 (2/thread). id: row=id>>3, col8=id&7
    const bf16_t* gAp[4]; int lA[4];
    const bf16_t* gBp[2]; int lB[2];
    #pragma unroll
    for (int n = 0; n < 4; n++) {
        const int id = t + n * 512;
        gAp[n] = Abf + (size_t)(i0 + (id >> 3)) * DDIM + (id & 7) * 8;
        lA[n]  = (id >> 3) * LDS_STRIDE + (id & 7) * 8;
    }
    #pragma unroll
    for (int n = 0; n < 2; n++) {
        const int id = t + n * 512;
        gBp[n] = Bbf + (size_t)(j0 + (id >> 3)) * DDIM + (id & 7) * 8;
        lB[n]  = (id >> 3) * LDS_STRIDE + (id & 7) * 8;
    }

    bf16x8 pfA[4], pfB[2];
    #pragma unroll
    for (int n = 0; n < 4; n++) pfA[n] = *(const bf16x8*)(gAp[n]);
    #pragma unroll
    for (int n = 0; n < 2; n++) pfB[n] = *(const bf16x8*)(gBp[n]);

    #pragma unroll 1
    for (int c = 0; c < DDIM / 64; ++c) {
        __syncthreads();   // previous chunk's readers done; LDS reusable
        #pragma unroll
        for (int n = 0; n < 4; n++) *(bf16x8*)(As + lA[n]) = pfA[n];
        #pragma unroll
        for (int n = 0; n < 2; n++) *(bf16x8*)(Bs + lB[n]) = pfB[n];
        __syncthreads();   // chunk c visible

        if (c < DDIM / 64 - 1) {
            const int k = (c + 1) * 64;
            #pragma unroll
            for (int n = 0; n < 4; n++) pfA[n] = *(const bf16x8*)(gAp[n] + k);
            #pragma unroll
            for (int n = 0; n < 2; n++) pfB[n] = *(const bf16x8*)(gBp[n] + k);
        }

        #pragma unroll
        for (int ks = 0; ks < 2; ks++) {
            bf16x8 af[4], bfr[4];
            #pragma unroll
            for (int mi = 0; mi < 4; mi++)
                af[mi] = *(const bf16x8*)(As + (wrow * 64 + mi * 16 + ln) * LDS_STRIDE
                                             + ks * 32 + q4 * 8);
            #pragma unroll
            for (int ni = 0; ni < 4; ni++)
                bfr[ni] = *(const bf16x8*)(Bs + (wcol * 64 + ni * 16 + ln) * LDS_STRIDE
                                              + ks * 32 + q4 * 8);
            #pragma unroll
            for (int mi = 0; mi < 4; mi++)
                #pragma unroll
                for (int ni = 0; ni < 4; ni++)
                    acc[mi][ni] = __builtin_amdgcn_mfma_f32_16x16x32_bf16(
                        af[mi], bfr[ni], acc[mi][ni], 0, 0, 0);
        }
    }

    // ---- epilogue (verified): C/D col = lane&15 (=j), row = quad*4+reg (=i) ----
    const int i_base = i0 + wrow * 64;
    const int j_base = j0 + wcol * 64;

    float e_j[4];
    #pragma unroll
    for (int ni = 0; ni < 4; ni++) e_j[ni] = e[j_base + ni * 16 + ln];

    #pragma unroll
    for (int mi = 0; mi < 4; mi++) {
        #pragma unroll
        for (int r = 0; r < 4; r++) {
            const int i = i_base + mi * 16 + q4 * 4 + r;
            const uint64_t m  = Lb[(size_t)i * 64 + (j_base >> 6)];
            const uint64_t ms = m >> ln;
            float cs = 0.f, cl = 0.f, el = 0.f;
            #pragma unroll
            for (int ni = 0; ni < 4; ni++) {
                float c = acc[mi][ni][r];
                cs += c;
                if ((ms >> (ni * 16)) & 1ull) { cl += c; el += e_j[ni]; }
            }
            #pragma unroll
            for (int s = 1; s < 16; s <<= 1) {
                cs += __shfl_xor(cs, s);
                cl += __shfl_xor(cl, s);
                el += __shfl_xor(el, s);
            }
            if (ln == 0) {
                atomicAdd(&CS[i], cs);
                atomicAdd(&CL[i], cl);
                atomicAdd(&EL[i], el);
            }
        }
    }
}

// ---------------------------------------------------------------------------
// Kernel 3: final — Etot = sum e; result = sum_i pos/neg
// ---------------------------------------------------------------------------
__global__ __launch_bounds__(256) void final_kernel(
    const float* __restrict__ e, const float* __restrict__ kld,
    const float* __restrict__ CS, const float* __restrict__ CL,
    const float* __restrict__ EL, float* __restrict__ out)
{
    __shared__ float sred[4];
    __shared__ float sEtot;
    const int t = threadIdx.x;

    float s = 0.f;
    for (int j = t; j < BROWS; j += 256) s += e[j];
    #pragma unroll
    for (int off = 32; off > 0; off >>= 1) s += __shfl_down(s, off);
    if ((t & 63) == 0) sred[t >> 6] = s;
    __syncthreads();
    if (t == 0) sEtot = sred[0] + sred[1] + sred[2] + sred[3];
    __syncthreads();
    const float Etot = sEtot;
    const float invD = 1.0f / DDIM;

    float rs = 0.f;
    for (int i = t; i < BROWS; i += 256) {
        float el = EL[i], cl = CL[i], cs = CS[i];
        float pos = kld[i] + (el - cl) * invD;
        float neg = (Etot - el - cs + cl) * invD;
        rs += pos / neg;
    }
    __syncthreads();
    #pragma unroll
    for (int off = 32; off > 0; off >>= 1) rs += __shfl_down(rs, off);
    if ((t & 63) == 0) sred[t >> 6] = rs;
    __syncthreads();
    if (t == 0) out[0] = sred[0] + sred[1] + sred[2] + sred[3];
}

// ---------------------------------------------------------------------------
extern "C" void kernel_launch(void* const* d_in, const int* in_sizes, int n_in,
                              void* d_out, int out_size, void* d_ws, size_t ws_size,
                              hipStream_t stream)
{
    const float* q = (const float*)d_in[0];
    const float* p = (const float*)d_in[1];
    const float* L = (const float*)d_in[2];
    float* out = (float*)d_out;

    char* ws = (char*)d_ws;
    bf16_t* lqb = (bf16_t*)ws;                                    // 8 MB
    bf16_t* pb  = (bf16_t*)(ws + (size_t)BROWS * DDIM * 2);       // 8 MB
    float*  e   = (float*)(ws + (size_t)BROWS * DDIM * 4);        // 16 KB
    float*  kld = e + BROWS;
    float*  CS  = kld + BROWS;
    float*  CL  = CS + BROWS;
    float*  EL  = CL + BROWS;
    uint64_t* Lb = (uint64_t*)(EL + BROWS);                       // 2 MB

    prep_kernel<<<BROWS, 256, 0, stream>>>(q, p, L, lqb, pb, Lb, e, kld, CS, CL, EL);

    dim3 grid(BROWS / 128, BROWS / 256);
    gemm_epi_kernel<<<grid, 512, 0, stream>>>(lqb, pb, Lb, e, CS, CL, EL);

    final_kernel<<<1, 256, 0, stream>>>(e, kld, CS, CL, EL, out);
}